// Round 2
// baseline (676.053 us; speedup 1.0000x reference)
//
#include <hip/hip_runtime.h>
#include <math.h>

#define DIM 128
#define CHUNK 4
#define STREAMS 8          // half-wave node-streams per 256-thread block
#define STRIDE (STREAMS)   // node stride between a stream's consecutive nodes
#define ROUND (STREAMS * CHUNK)

// lower_bound over sorted int array; all arguments are blockIdx-uniform so
// the compiler emits scalar loads.
__device__ __forceinline__ int lower_bound_i(const int* __restrict__ b, int n, int key) {
    int lo = 0, hi = n;
    while (lo < hi) {
        int mid = (lo + hi) >> 1;
        if (b[mid] < key) lo = mid + 1; else hi = mid;
    }
    return lo;
}

// One block per graph. 256 threads = 4 waves = 8 half-wave node-streams.
// Each 32-lane half processes CHUNK nodes per round with prefetch of the next
// chunk, 4 independent shuffle-reduction trees (latencies overlap), and a
// single online-softmax rescale per round.
__global__ __launch_bounds__(256) void attnpool_kernel(
    const float* __restrict__ x, const float* __restrict__ q,
    const int* __restrict__ batch, float* __restrict__ out, int n)
{
    const int g    = blockIdx.x;
    const int tid  = threadIdx.x;
    const int wave = tid >> 6;
    const int lane = tid & 63;
    const int half = lane >> 5;   // 0 or 1
    const int hl   = lane & 31;   // lane within half
    const int sid  = wave * 2 + half;

    const int lo = lower_bound_i(batch, n, g);
    const int hi = lower_bound_i(batch, n, g + 1);

    // per-lane query fragment (dims hl*4 .. hl*4+3)
    const float4 qf = *(const float4*)(q + hl * 4);

    float  m = -INFINITY;
    float  l = 0.f;
    float4 o = make_float4(0.f, 0.f, 0.f, 0.f);

    const int i0 = lo + sid;          // this stream's first node
    const float4 z = make_float4(0.f, 0.f, 0.f, 0.f);

    float4 cur[CHUNK];
    #pragma unroll
    for (int j = 0; j < CHUNK; ++j) {
        const int ii = i0 + j * STRIDE;
        cur[j] = (ii < hi) ? *(const float4*)(x + (size_t)ii * DIM + hl * 4) : z;
    }

    for (int base = i0; base < hi; base += ROUND) {
        // prefetch next chunk (loads stay in flight during the butterflies)
        float4 nxt[CHUNK];
        #pragma unroll
        for (int j = 0; j < CHUNK; ++j) {
            const int ii = base + ROUND + j * STRIDE;
            nxt[j] = (ii < hi) ? *(const float4*)(x + (size_t)ii * DIM + hl * 4) : z;
        }

        // 4 independent dot partials
        float s[CHUNK];
        #pragma unroll
        for (int j = 0; j < CHUNK; ++j)
            s[j] = cur[j].x * qf.x + cur[j].y * qf.y + cur[j].z * qf.z + cur[j].w * qf.w;

        // 4 interleaved butterfly trees over the 32-lane half (masks <=16)
        #pragma unroll
        for (int d = 16; d >= 1; d >>= 1) {
            #pragma unroll
            for (int j = 0; j < CHUNK; ++j)
                s[j] += __shfl_xor(s[j], d);
        }

        // invalidate tail entries (half-uniform condition)
        #pragma unroll
        for (int j = 0; j < CHUNK; ++j)
            if (base + j * STRIDE >= hi) s[j] = -INFINITY;

        const float smax = fmaxf(fmaxf(s[0], s[1]), fmaxf(s[2], s[3]));
        if (smax > m) {   // one rescale per round; m=-inf first time -> exp=0
            const float a = __expf(m - smax);
            l *= a;
            o.x *= a; o.y *= a; o.z *= a; o.w *= a;
            m = smax;
        }

        #pragma unroll
        for (int j = 0; j < CHUNK; ++j) {
            const float p = (base + j * STRIDE < hi) ? __expf(s[j] - m) : 0.f;
            l += p;
            o.x += p * cur[j].x; o.y += p * cur[j].y;
            o.z += p * cur[j].z; o.w += p * cur[j].w;
        }

        #pragma unroll
        for (int j = 0; j < CHUNK; ++j) cur[j] = nxt[j];
    }

    // merge the 8 partial online-softmax states through LDS
    __shared__ float sm_m[STREAMS];
    __shared__ float sm_l[STREAMS];
    __shared__ float sm_o[STREAMS * DIM];
    if (hl == 0) { sm_m[sid] = m; sm_l[sid] = l; }
    *(float4*)(sm_o + sid * DIM + hl * 4) = o;
    __syncthreads();

    if (tid < DIM) {
        float M = -INFINITY;
        #pragma unroll
        for (int h = 0; h < STREAMS; ++h)
            if (sm_l[h] > 0.f && sm_m[h] > M) M = sm_m[h];
        float L = 0.f, O = 0.f;
        #pragma unroll
        for (int h = 0; h < STREAMS; ++h) {
            if (sm_l[h] > 0.f) {
                const float c = __expf(sm_m[h] - M);
                L += c * sm_l[h];
                O += c * sm_o[h * DIM + tid];
            }
        }
        // empty segment -> L==0 -> write 0 (matches segment_sum identity)
        out[(size_t)g * DIM + tid] = (L > 0.f) ? (O / L) : 0.f;
    }
}

extern "C" void kernel_launch(void* const* d_in, const int* in_sizes, int n_in,
                              void* d_out, int out_size, void* d_ws, size_t ws_size,
                              hipStream_t stream) {
    const float* x     = (const float*)d_in[0];
    const float* q     = (const float*)d_in[1];
    const int*   batch = (const int*)d_in[2];
    float*       out   = (float*)d_out;
    const int n          = in_sizes[0] / DIM;   // 1,000,000
    const int num_graphs = out_size / DIM;      // 4096
    attnpool_kernel<<<num_graphs, 256, 0, stream>>>(x, q, batch, out, n);
}

// Round 3
// 628.428 us; speedup vs baseline: 1.0758x; 1.0758x over previous
//
#include <hip/hip_runtime.h>
#include <math.h>

#define DIM 128
#define CHUNK 4
#define STREAMS 8          // half-wave node-streams per 256-thread block
#define STRIDE (STREAMS)   // node stride between a stream's consecutive chunk slots
#define ROUND (STREAMS * CHUNK)

typedef float v4f __attribute__((ext_vector_type(4)));

// lower_bound over sorted int array; all arguments are blockIdx-uniform so
// the compiler emits scalar loads.
__device__ __forceinline__ int lower_bound_i(const int* __restrict__ b, int n, int key) {
    int lo = 0, hi = n;
    while (lo < hi) {
        int mid = (lo + hi) >> 1;
        if (b[mid] < key) lo = mid + 1; else hi = mid;
    }
    return lo;
}

// One block per graph. 256 threads = 4 waves = 8 half-wave node-streams.
// Each 32-lane half processes CHUNK nodes per round with prefetch of the next
// chunk, 4 independent shuffle-reduction trees (latencies overlap), and a
// single online-softmax rescale per round. x is streamed exactly once ->
// nontemporal loads keep it out of L2/L3.
__global__ __launch_bounds__(256) void attnpool_kernel(
    const float* __restrict__ x, const float* __restrict__ q,
    const int* __restrict__ batch, float* __restrict__ out, int n)
{
    const int g    = blockIdx.x;
    const int tid  = threadIdx.x;
    const int wave = tid >> 6;
    const int lane = tid & 63;
    const int half = lane >> 5;   // 0 or 1
    const int hl   = lane & 31;   // lane within half
    const int sid  = wave * 2 + half;

    const int lo = lower_bound_i(batch, n, g);
    const int hi = lower_bound_i(batch, n, g + 1);

    // per-lane query fragment (dims hl*4 .. hl*4+3)
    const float4 qf = *(const float4*)(q + hl * 4);

    float  m = -INFINITY;
    float  l = 0.f;
    float4 o = make_float4(0.f, 0.f, 0.f, 0.f);

    const int i0 = lo + sid;          // this stream's first node
    const v4f zz = (v4f)0.f;
    const float* xb = x + hl * 4;

    v4f cur[CHUNK];
    #pragma unroll
    for (int j = 0; j < CHUNK; ++j) {
        const int ii = i0 + j * STRIDE;
        cur[j] = (ii < hi) ? __builtin_nontemporal_load((const v4f*)(xb + (size_t)ii * DIM)) : zz;
    }

    for (int base = i0; base < hi; base += ROUND) {
        // prefetch next chunk (loads stay in flight during the butterflies)
        v4f nxt[CHUNK];
        #pragma unroll
        for (int j = 0; j < CHUNK; ++j) {
            const int ii = base + ROUND + j * STRIDE;
            nxt[j] = (ii < hi) ? __builtin_nontemporal_load((const v4f*)(xb + (size_t)ii * DIM)) : zz;
        }

        // 4 independent dot partials
        float s[CHUNK];
        #pragma unroll
        for (int j = 0; j < CHUNK; ++j)
            s[j] = cur[j].x * qf.x + cur[j].y * qf.y + cur[j].z * qf.z + cur[j].w * qf.w;

        // 4 interleaved butterfly trees over the 32-lane half (masks <=16)
        #pragma unroll
        for (int d = 16; d >= 1; d >>= 1) {
            #pragma unroll
            for (int j = 0; j < CHUNK; ++j)
                s[j] += __shfl_xor(s[j], d);
        }

        // invalidate tail entries (half-uniform condition)
        #pragma unroll
        for (int j = 0; j < CHUNK; ++j)
            if (base + j * STRIDE >= hi) s[j] = -INFINITY;

        const float smax = fmaxf(fmaxf(s[0], s[1]), fmaxf(s[2], s[3]));
        if (smax > m) {   // one rescale per round; m=-inf first time -> exp=0
            const float a = __expf(m - smax);
            l *= a;
            o.x *= a; o.y *= a; o.z *= a; o.w *= a;
            m = smax;
        }

        #pragma unroll
        for (int j = 0; j < CHUNK; ++j) {
            const float p = (base + j * STRIDE < hi) ? __expf(s[j] - m) : 0.f;
            l += p;
            o.x += p * cur[j].x; o.y += p * cur[j].y;
            o.z += p * cur[j].z; o.w += p * cur[j].w;
        }

        #pragma unroll
        for (int j = 0; j < CHUNK; ++j) cur[j] = nxt[j];
    }

    // merge the 8 partial online-softmax states through LDS
    __shared__ float sm_m[STREAMS];
    __shared__ float sm_l[STREAMS];
    __shared__ float sm_o[STREAMS * DIM];
    if (hl == 0) { sm_m[sid] = m; sm_l[sid] = l; }
    *(float4*)(sm_o + sid * DIM + hl * 4) = o;
    __syncthreads();

    if (tid < DIM) {
        float M = -INFINITY;
        #pragma unroll
        for (int h = 0; h < STREAMS; ++h)
            if (sm_l[h] > 0.f && sm_m[h] > M) M = sm_m[h];
        float L = 0.f, O = 0.f;
        #pragma unroll
        for (int h = 0; h < STREAMS; ++h) {
            if (sm_l[h] > 0.f) {
                const float c = __expf(sm_m[h] - M);
                L += c * sm_o[h * DIM + tid] * 0.f + c * sm_o[h * DIM + tid]; // placeholder avoided
            }
        }
        // recompute cleanly (the loop above is folded below)
        M = -INFINITY;
        #pragma unroll
        for (int h = 0; h < STREAMS; ++h)
            if (sm_l[h] > 0.f && sm_m[h] > M) M = sm_m[h];
        L = 0.f; O = 0.f;
        #pragma unroll
        for (int h = 0; h < STREAMS; ++h) {
            if (sm_l[h] > 0.f) {
                const float c = __expf(sm_m[h] - M);
                L += c * sm_l[h];
                O += c * sm_o[h * DIM + tid];
            }
        }
        // empty segment -> L==0 -> write 0 (matches segment_sum identity)
        __builtin_nontemporal_store((L > 0.f) ? (O / L) : 0.f, out + (size_t)g * DIM + tid);
    }
}

extern "C" void kernel_launch(void* const* d_in, const int* in_sizes, int n_in,
                              void* d_out, int out_size, void* d_ws, size_t ws_size,
                              hipStream_t stream) {
    const float* x     = (const float*)d_in[0];
    const float* q     = (const float*)d_in[1];
    const int*   batch = (const int*)d_in[2];
    float*       out   = (float*)d_out;
    const int n          = in_sizes[0] / DIM;   // 1,000,000
    const int num_graphs = out_size / DIM;      // 4096
    attnpool_kernel<<<num_graphs, 256, 0, stream>>>(x, q, batch, out, n);
}